// Round 1
// baseline (282.503 us; speedup 1.0000x reference)
//
#include <hip/hip_runtime.h>

// FactorizedDotProductAttention on MI355X (gfx950)
// B=8, N=3136 (=T16 * P196), C=768, H=12, hd=64. Heads 0-5: spatial attn over P=196
// per (b,t). Heads 6-11: temporal attn over T=16 per (b,p).
// Pipeline: x->bf16 ; pack W^T bf16 ; QKV GEMM (bf16 MFMA) ; spatial attn ; temporal attn ; out GEMM.

typedef __attribute__((ext_vector_type(8))) short short8;
typedef __attribute__((ext_vector_type(4))) float f32x4;

typedef __attribute__((address_space(1))) void gvoid;
typedef __attribute__((address_space(3))) void lvoid;

__device__ __forceinline__ unsigned short f2b(float f) {
  unsigned int u = __float_as_uint(f);
  unsigned int r = (u + 0x7FFFu + ((u >> 16) & 1u)) >> 16;  // RNE
  return (unsigned short)r;
}

// ---------- kernel 1: x (f32) -> bf16, plus pack qkv bias ----------
__global__ __launch_bounds__(256) void k_convert_x(
    const float* __restrict__ x, unsigned short* __restrict__ xb,
    const float* __restrict__ bq, const float* __restrict__ bk,
    const float* __restrict__ bv, float* __restrict__ bqkv) {
  int tid = blockIdx.x * 256 + threadIdx.x;  // exactly 19267584/4 threads
  if (tid < 2304)
    bqkv[tid] = tid < 768 ? bq[tid] : (tid < 1536 ? bk[tid - 768] : bv[tid - 1536]);
  float4 v = ((const float4*)x)[tid];
  ushort4 o;
  o.x = f2b(v.x); o.y = f2b(v.y); o.z = f2b(v.z); o.w = f2b(v.w);
  ((ushort4*)xb)[tid] = o;
}

// ---------- kernel 2: pack weights transposed to bf16 [N][K] ----------
// wqkvT[n][k] = W_{q|k|v}[k][n%768], n in [0,2304) ; woT[n][k] = Wo[k][n]
__global__ __launch_bounds__(256) void k_pack_w(
    const float* __restrict__ Wq, const float* __restrict__ Wk,
    const float* __restrict__ Wv, const float* __restrict__ Wo,
    unsigned short* __restrict__ wqkvT, unsigned short* __restrict__ woT) {
  __shared__ float tile[32][33];
  int bid = blockIdx.x;
  const float* W;
  unsigned short* dst;
  int n0, k0;
  if (bid < 1728) {  // 72 n-tiles * 24 k-tiles
    int tn = bid % 72, tk = bid / 72;
    n0 = tn * 32; k0 = tk * 32;
    int which = n0 / 768;  // tile never crosses a 768 boundary (768%32==0)
    W = which == 0 ? Wq : (which == 1 ? Wk : Wv);
    dst = wqkvT;
  } else {
    int b2 = bid - 1728;  // 24 * 24 tiles for Wo
    int tn = b2 % 24, tk = b2 / 24;
    n0 = tn * 32; k0 = tk * 32;
    W = Wo; dst = woT;
  }
  int nn0 = n0 % 768;
  for (int i = threadIdx.x; i < 1024; i += 256) {
    int r = i >> 5, c = i & 31;
    tile[r][c] = W[(size_t)(k0 + r) * 768 + nn0 + c];  // coalesced read
  }
  __syncthreads();
  for (int i = threadIdx.x; i < 1024; i += 256) {
    int r = i >> 5, c = i & 31;
    dst[(size_t)(n0 + r) * 768 + k0 + c] = f2b(tile[c][r]);  // coalesced write
  }
}

// ---------- GEMM: C[M][N] = A[M][K](bf16) * Bt[N][K]^T (bf16) + bias[N] ----------
// 128x128 tile, BK=32, 4 waves, global_load_lds(16B), 16x16x32 bf16 MFMA (m97 structure).
// M%128==0, N%128==0, K%32==0 guaranteed by caller.
template <int OUTF32>
__global__ __launch_bounds__(256) void k_gemm_bt(
    const unsigned short* __restrict__ A, const unsigned short* __restrict__ Bt,
    const float* __restrict__ bias, void* __restrict__ Cout,
    int M, int N, int K) {
  __shared__ __align__(16) unsigned short As[128 * 32];
  __shared__ __align__(16) unsigned short Bs[128 * 32];
  const int tid = threadIdx.x;
  const int w = tid >> 6, l = tid & 63;
  const int lg = l >> 4, ln = l & 15;
  const int m0 = blockIdx.y * 128, n0 = blockIdx.x * 128;
  const int wr = (w >> 1) * 64, wc = (w & 1) * 64;
  f32x4 acc[4][4] = {};
  // staging: thread tid covers row tid/4, k-chunk (tid&3)*8 (16B per lane, LDS linear)
  const unsigned short* ga = A + (size_t)(m0 + (tid >> 2)) * K + ((tid & 3) * 8);
  const unsigned short* gb = Bt + (size_t)(n0 + (tid >> 2)) * K + ((tid & 3) * 8);
  unsigned short* lAs = As + w * 512;  // wave-uniform LDS base (lane adds l*16B)
  unsigned short* lBs = Bs + w * 512;
  const size_t krow64 = (size_t)64 * K;
  for (int k0 = 0; k0 < K; k0 += 32) {
    __builtin_amdgcn_global_load_lds((const gvoid*)(ga + k0),          (lvoid*)lAs,          16, 0, 0);
    __builtin_amdgcn_global_load_lds((const gvoid*)(ga + krow64 + k0), (lvoid*)(lAs + 2048), 16, 0, 0);
    __builtin_amdgcn_global_load_lds((const gvoid*)(gb + k0),          (lvoid*)lBs,          16, 0, 0);
    __builtin_amdgcn_global_load_lds((const gvoid*)(gb + krow64 + k0), (lvoid*)(lBs + 2048), 16, 0, 0);
    __syncthreads();
    short8 a[4], b[4];
#pragma unroll
    for (int mt = 0; mt < 4; ++mt)
      a[mt] = *(const short8*)(As + (wr + mt * 16 + ln) * 32 + lg * 8);
#pragma unroll
    for (int nt = 0; nt < 4; ++nt)
      b[nt] = *(const short8*)(Bs + (wc + nt * 16 + ln) * 32 + lg * 8);
#pragma unroll
    for (int mt = 0; mt < 4; ++mt)
#pragma unroll
      for (int nt = 0; nt < 4; ++nt)
        acc[mt][nt] = __builtin_amdgcn_mfma_f32_16x16x32_bf16(a[mt], b[nt], acc[mt][nt], 0, 0, 0);
    __syncthreads();
  }
  // epilogue: C row = m0+wr+mt*16+lg*4+r, col = n0+wc+nt*16+ln
#pragma unroll
  for (int nt = 0; nt < 4; ++nt) {
    int col = n0 + wc + nt * 16 + ln;
    float bval = bias[col];
#pragma unroll
    for (int mt = 0; mt < 4; ++mt) {
      int row = m0 + wr + mt * 16 + lg * 4;
#pragma unroll
      for (int r = 0; r < 4; ++r) {
        float v = acc[mt][nt][r] + bval;
        if (OUTF32)
          ((float*)Cout)[(size_t)(row + r) * N + col] = v;
        else
          ((unsigned short*)Cout)[(size_t)(row + r) * N + col] = f2b(v);
      }
    }
  }
}

// ---------- spatial attention: heads 0-5, one block per (b,t,h) ----------
// S[p][q] = Q[p].K[q]/8 over q in [0,196); O = softmax(S) V
__global__ __launch_bounds__(256) void k_attn_spatial(
    const unsigned short* __restrict__ qkv, unsigned short* __restrict__ attn) {
  const int bi = blockIdx.x;  // 768 = 8*16*6
  const int h = bi % 6;
  const int t = (bi / 6) % 16;
  const int b = bi / 96;
  const int base_row = b * 3136 + t * 196;
  __shared__ __align__(16) unsigned short Vt[64][232];     // V^T[d][key], keys padded to 224
  __shared__ __align__(16) unsigned short Pl[4][16][232];  // per-wave P[m][key]
  // stage V^T (transpose 196x64 -> 64x224)
  for (int i = threadIdx.x; i < 196 * 64; i += 256) {
    int key = i >> 6, d = i & 63;
    Vt[d][key] = qkv[(size_t)(base_row + key) * 2304 + 1536 + h * 64 + d];
  }
  for (int i = threadIdx.x; i < 64 * 28; i += 256)
    Vt[i / 28][196 + (i % 28)] = 0;  // zero keys 196..223
  __syncthreads();
  const int w = threadIdx.x >> 6, l = threadIdx.x & 63;
  const int lg = l >> 4, ln = l & 15;
  const float scale = 0.125f;
  for (int mt = w; mt < 13; mt += 4) {  // 13 m-tiles of 16 query rows
    int qm = mt * 16 + ln; if (qm > 195) qm = 195;  // clamp padded rows (output masked later)
    const size_t qoff = (size_t)(base_row + qm) * 2304 + h * 64 + lg * 8;
    short8 qa0 = *(const short8*)(qkv + qoff);
    short8 qa1 = *(const short8*)(qkv + qoff + 32);
    f32x4 st[13];
#pragma unroll
    for (int nt = 0; nt < 13; ++nt) {
      int kn = nt * 16 + ln; if (kn > 195) kn = 195;
      const size_t koff = (size_t)(base_row + kn) * 2304 + 768 + h * 64 + lg * 8;
      short8 kb0 = *(const short8*)(qkv + koff);
      short8 kb1 = *(const short8*)(qkv + koff + 32);
      f32x4 s = {0.f, 0.f, 0.f, 0.f};
      s = __builtin_amdgcn_mfma_f32_16x16x32_bf16(qa0, kb0, s, 0, 0, 0);
      s = __builtin_amdgcn_mfma_f32_16x16x32_bf16(qa1, kb1, s, 0, 0, 0);
      st[nt] = s;
    }
    // scale + key mask ; row = mt*16 + lg*4 + r, its 16 scores per tile live in lanes of this group
    float mr[4] = {-1e30f, -1e30f, -1e30f, -1e30f};
#pragma unroll
    for (int nt = 0; nt < 13; ++nt) {
      bool valid = (nt * 16 + ln) < 196;
#pragma unroll
      for (int r = 0; r < 4; ++r) {
        float v = valid ? st[nt][r] * scale : -1e30f;
        st[nt][r] = v;
        mr[r] = fmaxf(mr[r], v);
      }
    }
#pragma unroll
    for (int msk = 1; msk <= 8; msk <<= 1)
#pragma unroll
      for (int r = 0; r < 4; ++r) mr[r] = fmaxf(mr[r], __shfl_xor(mr[r], msk));
    float sm[4] = {0.f, 0.f, 0.f, 0.f};
#pragma unroll
    for (int nt = 0; nt < 13; ++nt)
#pragma unroll
      for (int r = 0; r < 4; ++r) {
        float p = __expf(st[nt][r] - mr[r]);
        st[nt][r] = p;
        sm[r] += p;
      }
#pragma unroll
    for (int msk = 1; msk <= 8; msk <<= 1)
#pragma unroll
      for (int r = 0; r < 4; ++r) sm[r] += __shfl_xor(sm[r], msk);
    float inv[4];
#pragma unroll
    for (int r = 0; r < 4; ++r) inv[r] = 1.f / sm[r];
    // write P (C-layout -> LDS [m][key]) then zero pad keys 208..223
#pragma unroll
    for (int nt = 0; nt < 13; ++nt)
#pragma unroll
      for (int r = 0; r < 4; ++r)
        Pl[w][lg * 4 + r][nt * 16 + ln] = f2b(st[nt][r] * inv[r]);
#pragma unroll
    for (int r = 0; r < 4; ++r) Pl[w][ln][208 + lg * 4 + r] = 0;
    // O = P V : M=16 rows, N=64 (4 tiles), K=224 (7 steps)
#pragma unroll
    for (int nt4 = 0; nt4 < 4; ++nt4) {
      f32x4 acc = {0.f, 0.f, 0.f, 0.f};
#pragma unroll
      for (int ks = 0; ks < 7; ++ks) {
        short8 pa = *(const short8*)(&Pl[w][ln][ks * 32 + lg * 8]);
        short8 vb = *(const short8*)(&Vt[nt4 * 16 + ln][ks * 32 + lg * 8]);
        acc = __builtin_amdgcn_mfma_f32_16x16x32_bf16(pa, vb, acc, 0, 0, 0);
      }
#pragma unroll
      for (int r = 0; r < 4; ++r) {
        int m = mt * 16 + lg * 4 + r;
        if (m < 196)
          attn[(size_t)(base_row + m) * 768 + h * 64 + nt4 * 16 + ln] = f2b(acc[r]);
      }
    }
  }
}

// ---------- temporal attention: heads 6-11, one wave per (b,p,h) ----------
// S[t][s] = Q[t].K[s]/8 over s in [0,16); O = softmax(S) V
__global__ __launch_bounds__(256) void k_attn_temporal(
    const unsigned short* __restrict__ qkv, unsigned short* __restrict__ attn) {
  const int w = threadIdx.x >> 6, l = threadIdx.x & 63;
  const int u = blockIdx.x * 4 + w;  // 9408 = 8*196*6
  const int b = u / 1176;
  const int rem = u % 1176;
  const int p = rem / 6;
  const int h = 6 + rem % 6;
  const size_t rowb = (size_t)b * 3136 + p;
  __shared__ __align__(16) unsigned short Vt[4][64][40];  // V^T[d][t], t padded to 32
  __shared__ __align__(16) unsigned short Pl[4][16][40];
  for (int i = l; i < 1024; i += 64) {
    int tt = i >> 6, d = i & 63;
    Vt[w][d][tt] = qkv[(rowb + (size_t)tt * 196) * 2304 + 1536 + h * 64 + d];
  }
  for (int i = l; i < 1024; i += 64)
    Vt[w][i >> 4][16 + (i & 15)] = 0;  // zero keys 16..31
  const int lg = l >> 4, ln = l & 15;
  const size_t qoff = (rowb + (size_t)ln * 196) * 2304 + h * 64 + lg * 8;
  short8 qa0 = *(const short8*)(qkv + qoff);
  short8 qa1 = *(const short8*)(qkv + qoff + 32);
  short8 kb0 = *(const short8*)(qkv + qoff + 768);
  short8 kb1 = *(const short8*)(qkv + qoff + 768 + 32);
  f32x4 s = {0.f, 0.f, 0.f, 0.f};
  s = __builtin_amdgcn_mfma_f32_16x16x32_bf16(qa0, kb0, s, 0, 0, 0);
  s = __builtin_amdgcn_mfma_f32_16x16x32_bf16(qa1, kb1, s, 0, 0, 0);
  const float scale = 0.125f;
  float stv[4], mr[4];
#pragma unroll
  for (int r = 0; r < 4; ++r) { stv[r] = s[r] * scale; mr[r] = stv[r]; }
#pragma unroll
  for (int msk = 1; msk <= 8; msk <<= 1)
#pragma unroll
    for (int r = 0; r < 4; ++r) mr[r] = fmaxf(mr[r], __shfl_xor(mr[r], msk));
  float sm[4];
#pragma unroll
  for (int r = 0; r < 4; ++r) { stv[r] = __expf(stv[r] - mr[r]); sm[r] = stv[r]; }
#pragma unroll
  for (int msk = 1; msk <= 8; msk <<= 1)
#pragma unroll
    for (int r = 0; r < 4; ++r) sm[r] += __shfl_xor(sm[r], msk);
#pragma unroll
  for (int r = 0; r < 4; ++r)
    Pl[w][lg * 4 + r][ln] = f2b(stv[r] / sm[r]);
#pragma unroll
  for (int r = 0; r < 4; ++r) Pl[w][ln][16 + lg * 4 + r] = 0;  // zero keys 16..31
  // O = P V : M=16 (t), N=64 (4 tiles), K=32 (16 real keys + 16 zero)
  short8 pa = *(const short8*)(&Pl[w][ln][lg * 8]);
#pragma unroll
  for (int nt4 = 0; nt4 < 4; ++nt4) {
    short8 vb = *(const short8*)(&Vt[w][nt4 * 16 + ln][lg * 8]);
    f32x4 acc = {0.f, 0.f, 0.f, 0.f};
    acc = __builtin_amdgcn_mfma_f32_16x16x32_bf16(pa, vb, acc, 0, 0, 0);
#pragma unroll
    for (int r = 0; r < 4; ++r) {
      int tq = lg * 4 + r;
      attn[((size_t)b * 3136 + (size_t)tq * 196 + p) * 768 + h * 64 + nt4 * 16 + ln] = f2b(acc[r]);
    }
  }
}

// ---------- launch ----------
extern "C" void kernel_launch(void* const* d_in, const int* in_sizes, int n_in,
                              void* d_out, int out_size, void* d_ws, size_t ws_size,
                              hipStream_t stream) {
  const float* x  = (const float*)d_in[0];
  const float* Wq = (const float*)d_in[1];
  const float* bq = (const float*)d_in[2];
  const float* Wk = (const float*)d_in[3];
  const float* bk = (const float*)d_in[4];
  const float* Wv = (const float*)d_in[5];
  const float* bv = (const float*)d_in[6];
  const float* Wo = (const float*)d_in[7];
  const float* bo = (const float*)d_in[8];
  float* out = (float*)d_out;
  char* ws = (char*)d_ws;
  // workspace layout (bytes)
  unsigned short* xb    = (unsigned short*)(ws + 0);          // 25088*768*2   = 38,535,168
  unsigned short* wqkvT = (unsigned short*)(ws + 38535168);   // 2304*768*2    =  3,538,944
  float*          bqkv  = (float*)(ws + 42074112);            // 2304*4        =      9,216
  unsigned short* woT   = (unsigned short*)(ws + 42083328);   // 768*768*2     =  1,179,648
  unsigned short* qkvb  = (unsigned short*)(ws + 43262976);   // 25088*2304*2  = 115,605,504
  unsigned short* attnb = (unsigned short*)(ws + 158868480);  // 25088*768*2   = 38,535,168
  // total = 197,403,648 bytes

  k_convert_x<<<18816, 256, 0, stream>>>(x, xb, bq, bk, bv, bqkv);
  k_pack_w<<<2304, 256, 0, stream>>>(Wq, Wk, Wv, Wo, wqkvT, woT);
  k_gemm_bt<0><<<dim3(18, 196), 256, 0, stream>>>(xb, wqkvT, bqkv, (void*)qkvb, 25088, 2304, 768);
  k_attn_spatial<<<768, 256, 0, stream>>>(qkvb, attnb);
  k_attn_temporal<<<2352, 256, 0, stream>>>(qkvb, attnb);
  k_gemm_bt<1><<<dim3(6, 196), 256, 0, stream>>>(attnb, woT, bo, (void*)out, 25088, 768, 768);
}

// Round 2
// 257.457 us; speedup vs baseline: 1.0973x; 1.0973x over previous
//
#include <hip/hip_runtime.h>

// FactorizedDotProductAttention on MI355X (gfx950)
// B=8, N=3136 (=T16 * P196), C=768, H=12, hd=64. Heads 0-5: spatial attn over P=196
// per (b,t). Heads 6-11: temporal attn over T=16 per (b,p).
// Pipeline: x->bf16 ; pack W^T bf16 ; QKV GEMM (256^2 8-phase bf16 MFMA) ; spatial attn ;
// temporal attn ; out GEMM (128^2 m97-structure).

typedef __attribute__((ext_vector_type(8))) short short8;
typedef __attribute__((ext_vector_type(4))) float f32x4;

typedef __attribute__((address_space(1))) void gvoid;
typedef __attribute__((address_space(3))) void lvoid;

__device__ __forceinline__ unsigned short f2b(float f) {
  unsigned int u = __float_as_uint(f);
  unsigned int r = (u + 0x7FFFu + ((u >> 16) & 1u)) >> 16;  // RNE
  return (unsigned short)r;
}

// ---------- kernel 1: x (f32) -> bf16, plus pack qkv bias ----------
__global__ __launch_bounds__(256) void k_convert_x(
    const float* __restrict__ x, unsigned short* __restrict__ xb,
    const float* __restrict__ bq, const float* __restrict__ bk,
    const float* __restrict__ bv, float* __restrict__ bqkv) {
  int tid = blockIdx.x * 256 + threadIdx.x;  // exactly 19267584/4 threads
  if (tid < 2304)
    bqkv[tid] = tid < 768 ? bq[tid] : (tid < 1536 ? bk[tid - 768] : bv[tid - 1536]);
  float4 v = ((const float4*)x)[tid];
  ushort4 o;
  o.x = f2b(v.x); o.y = f2b(v.y); o.z = f2b(v.z); o.w = f2b(v.w);
  ((ushort4*)xb)[tid] = o;
}

// ---------- kernel 2: pack weights transposed to bf16 [N][K] ----------
__global__ __launch_bounds__(256) void k_pack_w(
    const float* __restrict__ Wq, const float* __restrict__ Wk,
    const float* __restrict__ Wv, const float* __restrict__ Wo,
    unsigned short* __restrict__ wqkvT, unsigned short* __restrict__ woT) {
  __shared__ float tile[32][33];
  int bid = blockIdx.x;
  const float* W;
  unsigned short* dst;
  int n0, k0;
  if (bid < 1728) {  // 72 n-tiles * 24 k-tiles
    int tn = bid % 72, tk = bid / 72;
    n0 = tn * 32; k0 = tk * 32;
    int which = n0 / 768;
    W = which == 0 ? Wq : (which == 1 ? Wk : Wv);
    dst = wqkvT;
  } else {
    int b2 = bid - 1728;
    int tn = b2 % 24, tk = b2 / 24;
    n0 = tn * 32; k0 = tk * 32;
    W = Wo; dst = woT;
  }
  int nn0 = n0 % 768;
  for (int i = threadIdx.x; i < 1024; i += 256) {
    int r = i >> 5, c = i & 31;
    tile[r][c] = W[(size_t)(k0 + r) * 768 + nn0 + c];
  }
  __syncthreads();
  for (int i = threadIdx.x; i < 1024; i += 256) {
    int r = i >> 5, c = i & 31;
    dst[(size_t)(n0 + r) * 768 + k0 + c] = f2b(tile[c][r]);
  }
}

// ================== 256x256 8-phase GEMM, K=768 fixed ==================
// A[M][768] bf16, Bt[N][768] bf16, C = A*Bt^T + bias. M%256==0, N%256==0.
// 8 waves (2m x 4n), wave tile 128x64 (rows mh*128+wm*64+mf*16, cols nh*128+wn*32+nf*16).
// LDS: A0|B0|A1|B1 buffers of 256x64 bf16 (32KB each) + 8KB dummy = 136KB.
// Swizzle: element granule g (16B) of row r stored at g ^ (r&7). Staged via
// pre-swizzled per-lane global source (linear LDS dest), read with same XOR.
// Schedule (race-free): zigzag quadrants (0,0)(0,1)(1,1)(1,0) per K-tile;
// stage targets regions whose last LDS-read completed a strictly earlier phase;
// vmcnt(4) at phases 4 & 8 (2 half-tiles in flight); dummy-redirect keeps
// vmcnt arithmetic uniform on the tail iteration.

#define FENCE asm volatile("" ::: "memory")
#define BARRIER do { FENCE; __builtin_amdgcn_s_barrier(); FENCE; } while (0)
#define WAIT_LGKM0 asm volatile("s_waitcnt lgkmcnt(0)" ::: "memory")
#define WAIT_VM4 asm volatile("s_waitcnt vmcnt(4)" ::: "memory")

#define STAGE(PBASE, BUFBASE, HT, KT_) do {                                          \
    int kt__ = (KT_);                                                                \
    bool real__ = (kt__ < 12);                                                       \
    if (!real__) kt__ -= 12;                                                         \
    const unsigned short* src__ = (PBASE) + (HT) * 98304 + kt__ * 64;                \
    unsigned d0__ = real__ ? ((BUFBASE) + (HT) * 8192 + w * 512) : (65536u + w * 512); \
    unsigned d1__ = real__ ? ((BUFBASE) + (HT) * 8192 + 4096 + w * 512) : (65536u + w * 512); \
    __builtin_amdgcn_global_load_lds((const gvoid*)src__, (lvoid*)(lds + d0__), 16, 0, 0); \
    __builtin_amdgcn_global_load_lds((const gvoid*)(src__ + 49152), (lvoid*)(lds + d1__), 16, 0, 0); \
  } while (0)

#define LDA(MH, ABASE) do {                                                          \
    const unsigned short* ab__ = lds + (ABASE) + ((MH) * 128 + arow) * 64;           \
    _Pragma("unroll")                                                                \
    for (int mf = 0; mf < 4; ++mf) {                                                 \
      af[mf][0] = *(const short8*)(ab__ + mf * 1024 + s0);                           \
      af[mf][1] = *(const short8*)(ab__ + mf * 1024 + s1);                           \
    }                                                                                \
  } while (0)

#define LDB(NH, BBASE) do {                                                          \
    const unsigned short* bb__ = lds + (BBASE) + ((NH) * 128 + brow) * 64;           \
    _Pragma("unroll")                                                                \
    for (int nf = 0; nf < 2; ++nf) {                                                 \
      bf[nf][0] = *(const short8*)(bb__ + nf * 1024 + s0);                           \
      bf[nf][1] = *(const short8*)(bb__ + nf * 1024 + s1);                           \
    }                                                                                \
  } while (0)

#define MM(MH, NH) do {                                                              \
    __builtin_amdgcn_s_setprio(1);                                                   \
    _Pragma("unroll")                                                                \
    for (int mf = 0; mf < 4; ++mf) {                                                 \
      _Pragma("unroll")                                                              \
      for (int nf = 0; nf < 2; ++nf) {                                               \
        acc[MH][mf][NH][nf] = __builtin_amdgcn_mfma_f32_16x16x32_bf16(               \
            af[mf][0], bf[nf][0], acc[MH][mf][NH][nf], 0, 0, 0);                     \
        acc[MH][mf][NH][nf] = __builtin_amdgcn_mfma_f32_16x16x32_bf16(               \
            af[mf][1], bf[nf][1], acc[MH][mf][NH][nf], 0, 0, 0);                     \
      }                                                                              \
    }                                                                                \
    __builtin_amdgcn_s_setprio(0);                                                   \
  } while (0)

__global__ __launch_bounds__(512, 2) void k_gemm256(
    const unsigned short* __restrict__ A, const unsigned short* __restrict__ Bt,
    const float* __restrict__ bias, unsigned short* __restrict__ Cout,
    int M, int N) {
  __shared__ __align__(16) unsigned short lds[69632];  // A0,B0,A1,B1 (16384 ea) + 4096 dummy
  // XCD-bijective block swizzle (m204)
  const int nwg = gridDim.x;
  const int nbx = N >> 8;
  const int orig = blockIdx.x;
  const int q = nwg >> 3, r = nwg & 7;
  const int xcd = orig & 7, lin = orig >> 3;
  const int wg = (xcd < r ? xcd * (q + 1) : r * (q + 1) + (xcd - r) * q) + lin;
  const int m0 = (wg / nbx) << 8, n0 = (wg % nbx) << 8;

  const int tid = threadIdx.x;
  const int w = tid >> 6, l = tid & 63;
  const int wm = w >> 2, wn = w & 3;
  const int lg = l >> 4, ln = l & 15;
  const int arow = wm * 64 + ln;
  const int brow = wn * 32 + ln;
  const int s0 = (lg ^ (ln & 7)) * 8;  // swizzled granule offset (elems), ks=0
  const int s1 = s0 ^ 32;              // ks=1
  // staging source (pre-swizzled): thread t covers row srow (+64 for j=1), granule (t&7)^(srow&7)
  const int srow = tid >> 3;
  const int slg8 = ((tid & 7) ^ (srow & 7)) * 8;
  const unsigned short* pA = A + (size_t)(m0 + srow) * 768 + slg8;
  const unsigned short* pB = Bt + (size_t)(n0 + srow) * 768 + slg8;

  f32x4 acc[2][4][2][2] = {};

  // prologue: buf0 <- kt0 (A-h0,B-h1,A-h1,B-h0), buf1 <- kt1 (A-h0,B-h1,A-h1); B1-h0 staged in ph1
  STAGE(pA, 0,     0, 0);
  STAGE(pB, 16384, 1, 0);
  STAGE(pA, 0,     1, 0);
  STAGE(pB, 16384, 0, 0);
  STAGE(pA, 32768, 0, 1);
  STAGE(pB, 49152, 1, 1);
  STAGE(pA, 32768, 1, 1);
  asm volatile("s_waitcnt vmcnt(6)" ::: "memory");  // buf0 complete (newest 3 HTs in flight)
  __builtin_amdgcn_s_barrier();
  FENCE;

  for (int it = 0; it < 6; ++it) {
    const int kt1 = 2 * it + 1, ktn0 = 2 * it + 2, ktn1 = 2 * it + 3;
    short8 af[4][2], bf[2][2];
    // ph1: quadrant (0,0) of buf0 ; stage B1-h0 (kt1)
    LDA(0, 0); LDB(0, 16384);
    STAGE(pB, 49152, 0, kt1);
    BARRIER; WAIT_LGKM0; MM(0, 0); BARRIER;
    // ph2: (0,1) ; stage A0-h0 (ktn0)
    LDB(1, 16384);
    STAGE(pA, 0, 0, ktn0);
    BARRIER; WAIT_LGKM0; MM(0, 1); BARRIER;
    // ph3: (1,1) ; stage B0-h1 (ktn0)
    LDA(1, 0);
    STAGE(pB, 16384, 1, ktn0);
    BARRIER; WAIT_LGKM0; MM(1, 1); BARRIER;
    // ph4: (1,0) ; stage A0-h1 (ktn0) ; vmcnt(4)
    LDB(0, 16384);
    STAGE(pA, 0, 1, ktn0);
    WAIT_VM4;
    BARRIER; WAIT_LGKM0; MM(1, 0); BARRIER;
    // ph5: (0,0) of buf1 ; stage B0-h0 (ktn0)
    LDA(0, 32768); LDB(0, 49152);
    STAGE(pB, 16384, 0, ktn0);
    BARRIER; WAIT_LGKM0; MM(0, 0); BARRIER;
    // ph6: (0,1) ; stage A1-h0 (ktn1)
    LDB(1, 49152);
    STAGE(pA, 32768, 0, ktn1);
    BARRIER; WAIT_LGKM0; MM(0, 1); BARRIER;
    // ph7: (1,1) ; stage B1-h1 (ktn1)
    LDA(1, 32768);
    STAGE(pB, 49152, 1, ktn1);
    BARRIER; WAIT_LGKM0; MM(1, 1); BARRIER;
    // ph8: (1,0) ; stage A1-h1 (ktn1) ; vmcnt(4)
    LDB(0, 49152);
    STAGE(pA, 32768, 1, ktn1);
    WAIT_VM4;
    BARRIER; WAIT_LGKM0; MM(1, 0); BARRIER;
  }

  // epilogue: row = m0 + mh*128 + wm*64 + mf*16 + lg*4 + rr ; col = n0 + nh*128 + wn*32 + nf*16 + ln
#pragma unroll
  for (int mh = 0; mh < 2; ++mh)
#pragma unroll
    for (int mf = 0; mf < 4; ++mf)
#pragma unroll
      for (int nh = 0; nh < 2; ++nh)
#pragma unroll
        for (int nf = 0; nf < 2; ++nf) {
          const int col = n0 + nh * 128 + wn * 32 + nf * 16 + ln;
          const float bval = bias[col];
          const int row = m0 + mh * 128 + wm * 64 + mf * 16 + lg * 4;
#pragma unroll
          for (int rr = 0; rr < 4; ++rr)
            Cout[(size_t)(row + rr) * N + col] = f2b(acc[mh][mf][nh][nf][rr] + bval);
        }
}

// ---------- GEMM: 128x128 m97-structure (kept for the output GEMM) ----------
template <int OUTF32>
__global__ __launch_bounds__(256) void k_gemm_bt(
    const unsigned short* __restrict__ A, const unsigned short* __restrict__ Bt,
    const float* __restrict__ bias, void* __restrict__ Cout,
    int M, int N, int K) {
  __shared__ __align__(16) unsigned short As[128 * 32];
  __shared__ __align__(16) unsigned short Bs[128 * 32];
  const int tid = threadIdx.x;
  const int w = tid >> 6, l = tid & 63;
  const int lg = l >> 4, ln = l & 15;
  const int m0 = blockIdx.y * 128, n0 = blockIdx.x * 128;
  const int wr = (w >> 1) * 64, wc = (w & 1) * 64;
  f32x4 acc[4][4] = {};
  const unsigned short* ga = A + (size_t)(m0 + (tid >> 2)) * K + ((tid & 3) * 8);
  const unsigned short* gb = Bt + (size_t)(n0 + (tid >> 2)) * K + ((tid & 3) * 8);
  unsigned short* lAs = As + w * 512;
  unsigned short* lBs = Bs + w * 512;
  const size_t krow64 = (size_t)64 * K;
  for (int k0 = 0; k0 < K; k0 += 32) {
    __builtin_amdgcn_global_load_lds((const gvoid*)(ga + k0),          (lvoid*)lAs,          16, 0, 0);
    __builtin_amdgcn_global_load_lds((const gvoid*)(ga + krow64 + k0), (lvoid*)(lAs + 2048), 16, 0, 0);
    __builtin_amdgcn_global_load_lds((const gvoid*)(gb + k0),          (lvoid*)lBs,          16, 0, 0);
    __builtin_amdgcn_global_load_lds((const gvoid*)(gb + krow64 + k0), (lvoid*)(lBs + 2048), 16, 0, 0);
    __syncthreads();
    short8 a[4], b[4];
#pragma unroll
    for (int mt = 0; mt < 4; ++mt)
      a[mt] = *(const short8*)(As + (wr + mt * 16 + ln) * 32 + lg * 8);
#pragma unroll
    for (int nt = 0; nt < 4; ++nt)
      b[nt] = *(const short8*)(Bs + (wc + nt * 16 + ln) * 32 + lg * 8);
#pragma unroll
    for (int mt = 0; mt < 4; ++mt)
#pragma unroll
      for (int nt = 0; nt < 4; ++nt)
        acc[mt][nt] = __builtin_amdgcn_mfma_f32_16x16x32_bf16(a[mt], b[nt], acc[mt][nt], 0, 0, 0);
    __syncthreads();
  }
#pragma unroll
  for (int nt = 0; nt < 4; ++nt) {
    int col = n0 + wc + nt * 16 + ln;
    float bval = bias[col];
#pragma unroll
    for (int mt = 0; mt < 4; ++mt) {
      int row = m0 + wr + mt * 16 + lg * 4;
#pragma unroll
      for (int r = 0; r < 4; ++r) {
        float v = acc[mt][nt][r] + bval;
        if (OUTF32)
          ((float*)Cout)[(size_t)(row + r) * N + col] = v;
        else
          ((unsigned short*)Cout)[(size_t)(row + r) * N + col] = f2b(v);
      }
    }
  }
}

// ---------- spatial attention: heads 0-5, one block per (b,t,h) ----------
__global__ __launch_bounds__(256) void k_attn_spatial(
    const unsigned short* __restrict__ qkv, unsigned short* __restrict__ attn) {
  const int bi = blockIdx.x;  // 768 = 8*16*6
  const int h = bi % 6;
  const int t = (bi / 6) % 16;
  const int b = bi / 96;
  const int base_row = b * 3136 + t * 196;
  __shared__ __align__(16) unsigned short Vt[64][232];
  __shared__ __align__(16) unsigned short Pl[4][16][232];
  for (int i = threadIdx.x; i < 196 * 64; i += 256) {
    int key = i >> 6, d = i & 63;
    Vt[d][key] = qkv[(size_t)(base_row + key) * 2304 + 1536 + h * 64 + d];
  }
  for (int i = threadIdx.x; i < 64 * 28; i += 256)
    Vt[i / 28][196 + (i % 28)] = 0;
  __syncthreads();
  const int w = threadIdx.x >> 6, l = threadIdx.x & 63;
  const int lg = l >> 4, ln = l & 15;
  const float scale = 0.125f;
  for (int mt = w; mt < 13; mt += 4) {
    int qm = mt * 16 + ln; if (qm > 195) qm = 195;
    const size_t qoff = (size_t)(base_row + qm) * 2304 + h * 64 + lg * 8;
    short8 qa0 = *(const short8*)(qkv + qoff);
    short8 qa1 = *(const short8*)(qkv + qoff + 32);
    f32x4 st[13];
#pragma unroll
    for (int nt = 0; nt < 13; ++nt) {
      int kn = nt * 16 + ln; if (kn > 195) kn = 195;
      const size_t koff = (size_t)(base_row + kn) * 2304 + 768 + h * 64 + lg * 8;
      short8 kb0 = *(const short8*)(qkv + koff);
      short8 kb1 = *(const short8*)(qkv + koff + 32);
      f32x4 s = {0.f, 0.f, 0.f, 0.f};
      s = __builtin_amdgcn_mfma_f32_16x16x32_bf16(qa0, kb0, s, 0, 0, 0);
      s = __builtin_amdgcn_mfma_f32_16x16x32_bf16(qa1, kb1, s, 0, 0, 0);
      st[nt] = s;
    }
    float mr[4] = {-1e30f, -1e30f, -1e30f, -1e30f};
#pragma unroll
    for (int nt = 0; nt < 13; ++nt) {
      bool valid = (nt * 16 + ln) < 196;
#pragma unroll
      for (int r = 0; r < 4; ++r) {
        float v = valid ? st[nt][r] * scale : -1e30f;
        st[nt][r] = v;
        mr[r] = fmaxf(mr[r], v);
      }
    }
#pragma unroll
    for (int msk = 1; msk <= 8; msk <<= 1)
#pragma unroll
      for (int r = 0; r < 4; ++r) mr[r] = fmaxf(mr[r], __shfl_xor(mr[r], msk));
    float sm[4] = {0.f, 0.f, 0.f, 0.f};
#pragma unroll
    for (int nt = 0; nt < 13; ++nt)
#pragma unroll
      for (int r = 0; r < 4; ++r) {
        float p = __expf(st[nt][r] - mr[r]);
        st[nt][r] = p;
        sm[r] += p;
      }
#pragma unroll
    for (int msk = 1; msk <= 8; msk <<= 1)
#pragma unroll
      for (int r = 0; r < 4; ++r) sm[r] += __shfl_xor(sm[r], msk);
    float inv[4];
#pragma unroll
    for (int r = 0; r < 4; ++r) inv[r] = 1.f / sm[r];
#pragma unroll
    for (int nt = 0; nt < 13; ++nt)
#pragma unroll
      for (int r = 0; r < 4; ++r)
        Pl[w][lg * 4 + r][nt * 16 + ln] = f2b(st[nt][r] * inv[r]);
#pragma unroll
    for (int r = 0; r < 4; ++r) Pl[w][ln][208 + lg * 4 + r] = 0;
#pragma unroll
    for (int nt4 = 0; nt4 < 4; ++nt4) {
      f32x4 acc = {0.f, 0.f, 0.f, 0.f};
#pragma unroll
      for (int ks = 0; ks < 7; ++ks) {
        short8 pa = *(const short8*)(&Pl[w][ln][ks * 32 + lg * 8]);
        short8 vb = *(const short8*)(&Vt[nt4 * 16 + ln][ks * 32 + lg * 8]);
        acc = __builtin_amdgcn_mfma_f32_16x16x32_bf16(pa, vb, acc, 0, 0, 0);
      }
#pragma unroll
      for (int r = 0; r < 4; ++r) {
        int m = mt * 16 + lg * 4 + r;
        if (m < 196)
          attn[(size_t)(base_row + m) * 768 + h * 64 + nt4 * 16 + ln] = f2b(acc[r]);
      }
    }
  }
}

// ---------- temporal attention: heads 6-11, one wave per (b,p,h) ----------
__global__ __launch_bounds__(256) void k_attn_temporal(
    const unsigned short* __restrict__ qkv, unsigned short* __restrict__ attn) {
  const int w = threadIdx.x >> 6, l = threadIdx.x & 63;
  const int u = blockIdx.x * 4 + w;  // 9408 = 8*196*6
  const int b = u / 1176;
  const int rem = u % 1176;
  const int p = rem / 6;
  const int h = 6 + rem % 6;
  const size_t rowb = (size_t)b * 3136 + p;
  __shared__ __align__(16) unsigned short Vt[4][64][40];
  __shared__ __align__(16) unsigned short Pl[4][16][40];
  for (int i = l; i < 1024; i += 64) {
    int tt = i >> 6, d = i & 63;
    Vt[w][d][tt] = qkv[(rowb + (size_t)tt * 196) * 2304 + 1536 + h * 64 + d];
  }
  for (int i = l; i < 1024; i += 64)
    Vt[w][i >> 4][16 + (i & 15)] = 0;
  const int lg = l >> 4, ln = l & 15;
  const size_t qoff = (rowb + (size_t)ln * 196) * 2304 + h * 64 + lg * 8;
  short8 qa0 = *(const short8*)(qkv + qoff);
  short8 qa1 = *(const short8*)(qkv + qoff + 32);
  short8 kb0 = *(const short8*)(qkv + qoff + 768);
  short8 kb1 = *(const short8*)(qkv + qoff + 768 + 32);
  f32x4 s = {0.f, 0.f, 0.f, 0.f};
  s = __builtin_amdgcn_mfma_f32_16x16x32_bf16(qa0, kb0, s, 0, 0, 0);
  s = __builtin_amdgcn_mfma_f32_16x16x32_bf16(qa1, kb1, s, 0, 0, 0);
  const float scale = 0.125f;
  float stv[4], mr[4];
#pragma unroll
  for (int r = 0; r < 4; ++r) { stv[r] = s[r] * scale; mr[r] = stv[r]; }
#pragma unroll
  for (int msk = 1; msk <= 8; msk <<= 1)
#pragma unroll
    for (int r = 0; r < 4; ++r) mr[r] = fmaxf(mr[r], __shfl_xor(mr[r], msk));
  float sm[4];
#pragma unroll
  for (int r = 0; r < 4; ++r) { stv[r] = __expf(stv[r] - mr[r]); sm[r] = stv[r]; }
#pragma unroll
  for (int msk = 1; msk <= 8; msk <<= 1)
#pragma unroll
    for (int r = 0; r < 4; ++r) sm[r] += __shfl_xor(sm[r], msk);
#pragma unroll
  for (int r = 0; r < 4; ++r)
    Pl[w][lg * 4 + r][ln] = f2b(stv[r] / sm[r]);
#pragma unroll
  for (int r = 0; r < 4; ++r) Pl[w][ln][16 + lg * 4 + r] = 0;
  short8 pa = *(const short8*)(&Pl[w][ln][lg * 8]);
#pragma unroll
  for (int nt4 = 0; nt4 < 4; ++nt4) {
    short8 vb = *(const short8*)(&Vt[w][nt4 * 16 + ln][lg * 8]);
    f32x4 acc = {0.f, 0.f, 0.f, 0.f};
    acc = __builtin_amdgcn_mfma_f32_16x16x32_bf16(pa, vb, acc, 0, 0, 0);
#pragma unroll
    for (int r = 0; r < 4; ++r) {
      int tq = lg * 4 + r;
      attn[((size_t)b * 3136 + (size_t)tq * 196 + p) * 768 + h * 64 + nt4 * 16 + ln] = f2b(acc[r]);
    }
  }
}

// ---------- launch ----------
extern "C" void kernel_launch(void* const* d_in, const int* in_sizes, int n_in,
                              void* d_out, int out_size, void* d_ws, size_t ws_size,
                              hipStream_t stream) {
  const float* x  = (const float*)d_in[0];
  const float* Wq = (const float*)d_in[1];
  const float* bq = (const float*)d_in[2];
  const float* Wk = (const float*)d_in[3];
  const float* bk = (const float*)d_in[4];
  const float* Wv = (const float*)d_in[5];
  const float* bv = (const float*)d_in[6];
  const float* Wo = (const float*)d_in[7];
  const float* bo = (const float*)d_in[8];
  float* out = (float*)d_out;
  char* ws = (char*)d_ws;
  unsigned short* xb    = (unsigned short*)(ws + 0);          // 25088*768*2
  unsigned short* wqkvT = (unsigned short*)(ws + 38535168);   // 2304*768*2
  float*          bqkv  = (float*)(ws + 42074112);            // 2304*4
  unsigned short* woT   = (unsigned short*)(ws + 42083328);   // 768*768*2
  unsigned short* qkvb  = (unsigned short*)(ws + 43262976);   // 25088*2304*2
  unsigned short* attnb = (unsigned short*)(ws + 158868480);  // 25088*768*2

  k_convert_x<<<18816, 256, 0, stream>>>(x, xb, bq, bk, bv, bqkv);
  k_pack_w<<<2304, 256, 0, stream>>>(Wq, Wk, Wv, Wo, wqkvT, woT);
  k_gemm256<<<882, 512, 0, stream>>>(xb, wqkvT, bqkv, qkvb, 25088, 2304);
  k_attn_spatial<<<768, 256, 0, stream>>>(qkvb, attnb);
  k_attn_temporal<<<2352, 256, 0, stream>>>(qkvb, attnb);
  k_gemm_bt<1><<<dim3(6, 196), 256, 0, stream>>>(attnb, woT, bo, (void*)out, 25088, 768, 768);
}

// Round 3
// 255.239 us; speedup vs baseline: 1.1068x; 1.0087x over previous
//
#include <hip/hip_runtime.h>

// FactorizedDotProductAttention on MI355X (gfx950)
// B=8, N=3136 (=T16 * P196), C=768, H=12, hd=64. Heads 0-5: spatial attn over P=196
// per (b,t). Heads 6-11: temporal attn over T=16 per (b,p).
// Pipeline: x->bf16 ; pack W^T bf16 ; QKV GEMM (256^2 8-phase bf16 MFMA) ; spatial attn ;
// temporal attn ; out GEMM (128^2 2-phase dbuf).

typedef __attribute__((ext_vector_type(8))) short short8;
typedef __attribute__((ext_vector_type(4))) float f32x4;

typedef __attribute__((address_space(1))) void gvoid;
typedef __attribute__((address_space(3))) void lvoid;

__device__ __forceinline__ unsigned short f2b(float f) {
  unsigned int u = __float_as_uint(f);
  unsigned int r = (u + 0x7FFFu + ((u >> 16) & 1u)) >> 16;  // RNE
  return (unsigned short)r;
}

// ---------- kernel 1: x (f32) -> bf16, plus pack qkv bias ----------
__global__ __launch_bounds__(256) void k_convert_x(
    const float* __restrict__ x, unsigned short* __restrict__ xb,
    const float* __restrict__ bq, const float* __restrict__ bk,
    const float* __restrict__ bv, float* __restrict__ bqkv) {
  int tid = blockIdx.x * 256 + threadIdx.x;  // exactly 19267584/4 threads
  if (tid < 2304)
    bqkv[tid] = tid < 768 ? bq[tid] : (tid < 1536 ? bk[tid - 768] : bv[tid - 1536]);
  float4 v = ((const float4*)x)[tid];
  ushort4 o;
  o.x = f2b(v.x); o.y = f2b(v.y); o.z = f2b(v.z); o.w = f2b(v.w);
  ((ushort4*)xb)[tid] = o;
}

// ---------- kernel 2: pack weights transposed to bf16 [N][K] ----------
__global__ __launch_bounds__(256) void k_pack_w(
    const float* __restrict__ Wq, const float* __restrict__ Wk,
    const float* __restrict__ Wv, const float* __restrict__ Wo,
    unsigned short* __restrict__ wqkvT, unsigned short* __restrict__ woT) {
  __shared__ float tile[32][33];
  int bid = blockIdx.x;
  const float* W;
  unsigned short* dst;
  int n0, k0;
  if (bid < 1728) {  // 72 n-tiles * 24 k-tiles
    int tn = bid % 72, tk = bid / 72;
    n0 = tn * 32; k0 = tk * 32;
    int which = n0 / 768;
    W = which == 0 ? Wq : (which == 1 ? Wk : Wv);
    dst = wqkvT;
  } else {
    int b2 = bid - 1728;
    int tn = b2 % 24, tk = b2 / 24;
    n0 = tn * 32; k0 = tk * 32;
    W = Wo; dst = woT;
  }
  int nn0 = n0 % 768;
  for (int i = threadIdx.x; i < 1024; i += 256) {
    int r = i >> 5, c = i & 31;
    tile[r][c] = W[(size_t)(k0 + r) * 768 + nn0 + c];
  }
  __syncthreads();
  for (int i = threadIdx.x; i < 1024; i += 256) {
    int r = i >> 5, c = i & 31;
    dst[(size_t)(n0 + r) * 768 + k0 + c] = f2b(tile[c][r]);
  }
}

// ================== 256x256 8-phase GEMM, K=768 fixed ==================
// 8 waves (2m x 4n), wave tile 128x64. LDS: A0|B0|A1|B1 (32KB ea) + 8KB dummy.
// Swizzle: 16B granule g of row r stored at g ^ (r&7), both-sides (T2/rule 21).
// Counted vmcnt(6) at ph4/ph8: the 6 newest load-instrs (3 STAGEs) are exactly
// the ones not needed until >=2 phases later; everything older must be complete.

#define FENCE asm volatile("" ::: "memory")
#define BARRIER do { FENCE; __builtin_amdgcn_s_barrier(); FENCE; } while (0)
#define WAIT_LGKM0 asm volatile("s_waitcnt lgkmcnt(0)" ::: "memory")
#define WAIT_VM6 asm volatile("s_waitcnt vmcnt(6)" ::: "memory")

#define STAGE(PBASE, BUFBASE, HT, KT_) do {                                          \
    int kt__ = (KT_);                                                                \
    bool real__ = (kt__ < 12);                                                       \
    if (!real__) kt__ -= 12;                                                         \
    const unsigned short* src__ = (PBASE) + (HT) * 98304 + kt__ * 64;                \
    unsigned d0__ = real__ ? ((BUFBASE) + (HT) * 8192 + w * 512) : (65536u + w * 512); \
    unsigned d1__ = real__ ? ((BUFBASE) + (HT) * 8192 + 4096 + w * 512) : (65536u + w * 512); \
    __builtin_amdgcn_global_load_lds((const gvoid*)src__, (lvoid*)(lds + d0__), 16, 0, 0); \
    __builtin_amdgcn_global_load_lds((const gvoid*)(src__ + 49152), (lvoid*)(lds + d1__), 16, 0, 0); \
  } while (0)

#define LDA(MH, ABASE) do {                                                          \
    const unsigned short* ab__ = lds + (ABASE) + ((MH) * 128 + arow) * 64;           \
    _Pragma("unroll")                                                                \
    for (int mf = 0; mf < 4; ++mf) {                                                 \
      af[mf][0] = *(const short8*)(ab__ + mf * 1024 + s0);                           \
      af[mf][1] = *(const short8*)(ab__ + mf * 1024 + s1);                           \
    }                                                                                \
  } while (0)

#define LDB(NH, BBASE) do {                                                          \
    const unsigned short* bb__ = lds + (BBASE) + ((NH) * 128 + brow) * 64;           \
    _Pragma("unroll")                                                                \
    for (int nf = 0; nf < 2; ++nf) {                                                 \
      bf[nf][0] = *(const short8*)(bb__ + nf * 1024 + s0);                           \
      bf[nf][1] = *(const short8*)(bb__ + nf * 1024 + s1);                           \
    }                                                                                \
  } while (0)

#define MM(MH, NH) do {                                                              \
    __builtin_amdgcn_s_setprio(1);                                                   \
    _Pragma("unroll")                                                                \
    for (int mf = 0; mf < 4; ++mf) {                                                 \
      _Pragma("unroll")                                                              \
      for (int nf = 0; nf < 2; ++nf) {                                               \
        acc[MH][mf][NH][nf] = __builtin_amdgcn_mfma_f32_16x16x32_bf16(               \
            af[mf][0], bf[nf][0], acc[MH][mf][NH][nf], 0, 0, 0);                     \
        acc[MH][mf][NH][nf] = __builtin_amdgcn_mfma_f32_16x16x32_bf16(               \
            af[mf][1], bf[nf][1], acc[MH][mf][NH][nf], 0, 0, 0);                     \
      }                                                                              \
    }                                                                                \
    __builtin_amdgcn_s_setprio(0);                                                   \
  } while (0)

__global__ __launch_bounds__(512, 2) void k_gemm256(
    const unsigned short* __restrict__ A, const unsigned short* __restrict__ Bt,
    const float* __restrict__ bias, unsigned short* __restrict__ Cout,
    int M, int N) {
  __shared__ __align__(16) unsigned short lds[69632];  // A0,B0,A1,B1 (16384 ea) + 4096 dummy
  // XCD-bijective block swizzle (m204)
  const int nwg = gridDim.x;
  const int nbx = N >> 8;
  const int orig = blockIdx.x;
  const int q = nwg >> 3, r = nwg & 7;
  const int xcd = orig & 7, lin = orig >> 3;
  const int wg = (xcd < r ? xcd * (q + 1) : r * (q + 1) + (xcd - r) * q) + lin;
  const int m0 = (wg / nbx) << 8, n0 = (wg % nbx) << 8;

  const int tid = threadIdx.x;
  const int w = tid >> 6, l = tid & 63;
  const int wm = w >> 2, wn = w & 3;
  const int lg = l >> 4, ln = l & 15;
  const int arow = wm * 64 + ln;
  const int brow = wn * 32 + ln;
  const int s0 = (lg ^ (ln & 7)) * 8;  // swizzled granule offset (elems), ks=0
  const int s1 = s0 ^ 32;              // ks=1
  const int srow = tid >> 3;
  const int slg8 = ((tid & 7) ^ (srow & 7)) * 8;
  const unsigned short* pA = A + (size_t)(m0 + srow) * 768 + slg8;
  const unsigned short* pB = Bt + (size_t)(n0 + srow) * 768 + slg8;

  f32x4 acc[2][4][2][2] = {};

  // prologue: buf0 <- kt0, buf1 <- kt1 (minus B1-h0, staged in ph1)
  STAGE(pA, 0,     0, 0);
  STAGE(pB, 16384, 1, 0);
  STAGE(pA, 0,     1, 0);
  STAGE(pB, 16384, 0, 0);
  STAGE(pA, 32768, 0, 1);
  STAGE(pB, 49152, 1, 1);
  STAGE(pA, 32768, 1, 1);
  asm volatile("s_waitcnt vmcnt(6)" ::: "memory");  // buf0 complete (newest 3 STAGEs in flight)
  __builtin_amdgcn_s_barrier();
  FENCE;

  for (int it = 0; it < 6; ++it) {
    const int kt1 = 2 * it + 1, ktn0 = 2 * it + 2, ktn1 = 2 * it + 3;
    short8 af[4][2], bf[2][2];
    // ph1: quadrant (0,0) of buf0 ; stage B1-h0 (kt1)
    LDA(0, 0); LDB(0, 16384);
    STAGE(pB, 49152, 0, kt1);
    BARRIER; WAIT_LGKM0; MM(0, 0); BARRIER;
    // ph2: (0,1) ; stage A0-h0 (ktn0)
    LDB(1, 16384);
    STAGE(pA, 0, 0, ktn0);
    BARRIER; WAIT_LGKM0; MM(0, 1); BARRIER;
    // ph3: (1,1) ; stage B0-h1 (ktn0)
    LDA(1, 0);
    STAGE(pB, 16384, 1, ktn0);
    BARRIER; WAIT_LGKM0; MM(1, 1); BARRIER;
    // ph4: (1,0) ; stage A0-h1 (ktn0) ; counted vmcnt(6)
    LDB(0, 16384);
    STAGE(pA, 0, 1, ktn0);
    WAIT_VM6;
    BARRIER; WAIT_LGKM0; MM(1, 0); BARRIER;
    // ph5: (0,0) of buf1 ; stage B0-h0 (ktn0)
    LDA(0, 32768); LDB(0, 49152);
    STAGE(pB, 16384, 0, ktn0);
    BARRIER; WAIT_LGKM0; MM(0, 0); BARRIER;
    // ph6: (0,1) ; stage A1-h0 (ktn1)
    LDB(1, 49152);
    STAGE(pA, 32768, 0, ktn1);
    BARRIER; WAIT_LGKM0; MM(0, 1); BARRIER;
    // ph7: (1,1) ; stage B1-h1 (ktn1)
    LDA(1, 32768);
    STAGE(pB, 49152, 1, ktn1);
    BARRIER; WAIT_LGKM0; MM(1, 1); BARRIER;
    // ph8: (1,0) ; stage A1-h1 (ktn1) ; counted vmcnt(6)
    LDB(0, 49152);
    STAGE(pA, 32768, 1, ktn1);
    WAIT_VM6;
    BARRIER; WAIT_LGKM0; MM(1, 0); BARRIER;
  }

#pragma unroll
  for (int mh = 0; mh < 2; ++mh)
#pragma unroll
    for (int mf = 0; mf < 4; ++mf)
#pragma unroll
      for (int nh = 0; nh < 2; ++nh)
#pragma unroll
        for (int nf = 0; nf < 2; ++nf) {
          const int col = n0 + nh * 128 + wn * 32 + nf * 16 + ln;
          const float bval = bias[col];
          const int row = m0 + mh * 128 + wm * 64 + mf * 16 + lg * 4;
#pragma unroll
          for (int rr = 0; rr < 4; ++rr)
            Cout[(size_t)(row + rr) * N + col] = f2b(acc[mh][mf][nh][nf][rr] + bval);
        }
}

// ---------- out GEMM: 128x128, BK=32, double-buffered 2-phase (T3-min) ----------
// stage(next) issued BEFORE compute(cur) so the vmcnt(0) drain overlaps a full
// compute phase; 32KB LDS keeps ~4 blocks/CU implicit overlap. f32 output.
__global__ __launch_bounds__(256) void k_gemm_out(
    const unsigned short* __restrict__ A, const unsigned short* __restrict__ Bt,
    const float* __restrict__ bias, float* __restrict__ C,
    int M, int N, int K) {
  __shared__ __align__(16) unsigned short As[2][128 * 32];
  __shared__ __align__(16) unsigned short Bs[2][128 * 32];
  const int tid = threadIdx.x;
  const int w = tid >> 6, l = tid & 63;
  const int lg = l >> 4, ln = l & 15;
  const int m0 = blockIdx.y * 128, n0 = blockIdx.x * 128;
  const int wr = (w >> 1) * 64, wc = (w & 1) * 64;
  f32x4 acc[4][4] = {};
  const unsigned short* ga = A + (size_t)(m0 + (tid >> 2)) * K + ((tid & 3) * 8);
  const unsigned short* gb = Bt + (size_t)(n0 + (tid >> 2)) * K + ((tid & 3) * 8);
  const size_t krow64 = (size_t)64 * K;
  const int wofs = w * 512;

#define OSTAGE(CO, K0) do {                                                                        \
    __builtin_amdgcn_global_load_lds((const gvoid*)(ga + (K0)),          (lvoid*)(&As[0][0] + (CO) + wofs),        16, 0, 0); \
    __builtin_amdgcn_global_load_lds((const gvoid*)(ga + krow64 + (K0)), (lvoid*)(&As[0][0] + (CO) + 2048 + wofs), 16, 0, 0); \
    __builtin_amdgcn_global_load_lds((const gvoid*)(gb + (K0)),          (lvoid*)(&Bs[0][0] + (CO) + wofs),        16, 0, 0); \
    __builtin_amdgcn_global_load_lds((const gvoid*)(gb + krow64 + (K0)), (lvoid*)(&Bs[0][0] + (CO) + 2048 + wofs), 16, 0, 0); \
  } while (0)

  OSTAGE(0, 0);
  asm volatile("s_waitcnt vmcnt(0)" ::: "memory");
  BARRIER;
  int co = 0;
  for (int k0 = 0; k0 < K; k0 += 32) {
    if (k0 + 32 < K) OSTAGE(co ^ 4096, k0 + 32);  // prefetch next tile into other buffer
    const unsigned short* as = &As[0][0] + co;
    const unsigned short* bs = &Bs[0][0] + co;
    short8 a[4], b[4];
#pragma unroll
    for (int mt = 0; mt < 4; ++mt)
      a[mt] = *(const short8*)(as + (wr + mt * 16 + ln) * 32 + lg * 8);
#pragma unroll
    for (int nt = 0; nt < 4; ++nt)
      b[nt] = *(const short8*)(bs + (wc + nt * 16 + ln) * 32 + lg * 8);
#pragma unroll
    for (int mt = 0; mt < 4; ++mt)
#pragma unroll
      for (int nt = 0; nt < 4; ++nt)
        acc[mt][nt] = __builtin_amdgcn_mfma_f32_16x16x32_bf16(a[mt], b[nt], acc[mt][nt], 0, 0, 0);
    asm volatile("s_waitcnt vmcnt(0)" ::: "memory");  // next-tile loads landed (overlapped with MFMA)
    BARRIER;
    co ^= 4096;
  }
#pragma unroll
  for (int nt = 0; nt < 4; ++nt) {
    int col = n0 + wc + nt * 16 + ln;
    float bval = bias[col];
#pragma unroll
    for (int mt = 0; mt < 4; ++mt) {
      int row = m0 + wr + mt * 16 + lg * 4;
#pragma unroll
      for (int r = 0; r < 4; ++r)
        C[(size_t)(row + r) * N + col] = acc[mt][nt][r] + bval;
    }
  }
#undef OSTAGE
}

// ---------- spatial attention: heads 0-5, one block per (b,t,h) ----------
__global__ __launch_bounds__(256) void k_attn_spatial(
    const unsigned short* __restrict__ qkv, unsigned short* __restrict__ attn) {
  const int bi = blockIdx.x;  // 768 = 8*16*6
  const int h = bi % 6;
  const int t = (bi / 6) % 16;
  const int b = bi / 96;
  const int base_row = b * 3136 + t * 196;
  __shared__ __align__(16) unsigned short Vt[64][232];
  __shared__ __align__(16) unsigned short Pl[4][16][232];
  for (int i = threadIdx.x; i < 196 * 64; i += 256) {
    int key = i >> 6, d = i & 63;
    Vt[d][key] = qkv[(size_t)(base_row + key) * 2304 + 1536 + h * 64 + d];
  }
  for (int i = threadIdx.x; i < 64 * 28; i += 256)
    Vt[i / 28][196 + (i % 28)] = 0;
  __syncthreads();
  const int w = threadIdx.x >> 6, l = threadIdx.x & 63;
  const int lg = l >> 4, ln = l & 15;
  const float scale = 0.125f;
  for (int mt = w; mt < 13; mt += 4) {
    int qm = mt * 16 + ln; if (qm > 195) qm = 195;
    const size_t qoff = (size_t)(base_row + qm) * 2304 + h * 64 + lg * 8;
    short8 qa0 = *(const short8*)(qkv + qoff);
    short8 qa1 = *(const short8*)(qkv + qoff + 32);
    f32x4 st[13];
#pragma unroll
    for (int nt = 0; nt < 13; ++nt) {
      int kn = nt * 16 + ln; if (kn > 195) kn = 195;
      const size_t koff = (size_t)(base_row + kn) * 2304 + 768 + h * 64 + lg * 8;
      short8 kb0 = *(const short8*)(qkv + koff);
      short8 kb1 = *(const short8*)(qkv + koff + 32);
      f32x4 s = {0.f, 0.f, 0.f, 0.f};
      s = __builtin_amdgcn_mfma_f32_16x16x32_bf16(qa0, kb0, s, 0, 0, 0);
      s = __builtin_amdgcn_mfma_f32_16x16x32_bf16(qa1, kb1, s, 0, 0, 0);
      st[nt] = s;
    }
    float mr[4] = {-1e30f, -1e30f, -1e30f, -1e30f};
#pragma unroll
    for (int nt = 0; nt < 13; ++nt) {
      bool valid = (nt * 16 + ln) < 196;
#pragma unroll
      for (int r = 0; r < 4; ++r) {
        float v = valid ? st[nt][r] * scale : -1e30f;
        st[nt][r] = v;
        mr[r] = fmaxf(mr[r], v);
      }
    }
#pragma unroll
    for (int msk = 1; msk <= 8; msk <<= 1)
#pragma unroll
      for (int r = 0; r < 4; ++r) mr[r] = fmaxf(mr[r], __shfl_xor(mr[r], msk));
    float sm[4] = {0.f, 0.f, 0.f, 0.f};
#pragma unroll
    for (int nt = 0; nt < 13; ++nt)
#pragma unroll
      for (int r = 0; r < 4; ++r) {
        float p = __expf(st[nt][r] - mr[r]);
        st[nt][r] = p;
        sm[r] += p;
      }
#pragma unroll
    for (int msk = 1; msk <= 8; msk <<= 1)
#pragma unroll
      for (int r = 0; r < 4; ++r) sm[r] += __shfl_xor(sm[r], msk);
    float inv[4];
#pragma unroll
    for (int r = 0; r < 4; ++r) inv[r] = 1.f / sm[r];
#pragma unroll
    for (int nt = 0; nt < 13; ++nt)
#pragma unroll
      for (int r = 0; r < 4; ++r)
        Pl[w][lg * 4 + r][nt * 16 + ln] = f2b(st[nt][r] * inv[r]);
#pragma unroll
    for (int r = 0; r < 4; ++r) Pl[w][ln][208 + lg * 4 + r] = 0;
#pragma unroll
    for (int nt4 = 0; nt4 < 4; ++nt4) {
      f32x4 acc = {0.f, 0.f, 0.f, 0.f};
#pragma unroll
      for (int ks = 0; ks < 7; ++ks) {
        short8 pa = *(const short8*)(&Pl[w][ln][ks * 32 + lg * 8]);
        short8 vb = *(const short8*)(&Vt[nt4 * 16 + ln][ks * 32 + lg * 8]);
        acc = __builtin_amdgcn_mfma_f32_16x16x32_bf16(pa, vb, acc, 0, 0, 0);
      }
#pragma unroll
      for (int r = 0; r < 4; ++r) {
        int m = mt * 16 + lg * 4 + r;
        if (m < 196)
          attn[(size_t)(base_row + m) * 768 + h * 64 + nt4 * 16 + ln] = f2b(acc[r]);
      }
    }
  }
}

// ---------- temporal attention: heads 6-11, one wave per (b,p,h) ----------
__global__ __launch_bounds__(256) void k_attn_temporal(
    const unsigned short* __restrict__ qkv, unsigned short* __restrict__ attn) {
  const int w = threadIdx.x >> 6, l = threadIdx.x & 63;
  const int u = blockIdx.x * 4 + w;  // 9408 = 8*196*6
  const int b = u / 1176;
  const int rem = u % 1176;
  const int p = rem / 6;
  const int h = 6 + rem % 6;
  const size_t rowb = (size_t)b * 3136 + p;
  __shared__ __align__(16) unsigned short Vt[4][64][40];
  __shared__ __align__(16) unsigned short Pl[4][16][40];
  for (int i = l; i < 1024; i += 64) {
    int tt = i >> 6, d = i & 63;
    Vt[w][d][tt] = qkv[(rowb + (size_t)tt * 196) * 2304 + 1536 + h * 64 + d];
  }
  for (int i = l; i < 1024; i += 64)
    Vt[w][i >> 4][16 + (i & 15)] = 0;
  const int lg = l >> 4, ln = l & 15;
  const size_t qoff = (rowb + (size_t)ln * 196) * 2304 + h * 64 + lg * 8;
  short8 qa0 = *(const short8*)(qkv + qoff);
  short8 qa1 = *(const short8*)(qkv + qoff + 32);
  short8 kb0 = *(const short8*)(qkv + qoff + 768);
  short8 kb1 = *(const short8*)(qkv + qoff + 768 + 32);
  f32x4 s = {0.f, 0.f, 0.f, 0.f};
  s = __builtin_amdgcn_mfma_f32_16x16x32_bf16(qa0, kb0, s, 0, 0, 0);
  s = __builtin_amdgcn_mfma_f32_16x16x32_bf16(qa1, kb1, s, 0, 0, 0);
  const float scale = 0.125f;
  float stv[4], mr[4];
#pragma unroll
  for (int r = 0; r < 4; ++r) { stv[r] = s[r] * scale; mr[r] = stv[r]; }
#pragma unroll
  for (int msk = 1; msk <= 8; msk <<= 1)
#pragma unroll
    for (int r = 0; r < 4; ++r) mr[r] = fmaxf(mr[r], __shfl_xor(mr[r], msk));
  float sm[4];
#pragma unroll
  for (int r = 0; r < 4; ++r) { stv[r] = __expf(stv[r] - mr[r]); sm[r] = stv[r]; }
#pragma unroll
  for (int msk = 1; msk <= 8; msk <<= 1)
#pragma unroll
    for (int r = 0; r < 4; ++r) sm[r] += __shfl_xor(sm[r], msk);
#pragma unroll
  for (int r = 0; r < 4; ++r)
    Pl[w][lg * 4 + r][ln] = f2b(stv[r] / sm[r]);
#pragma unroll
  for (int r = 0; r < 4; ++r) Pl[w][ln][16 + lg * 4 + r] = 0;
  short8 pa = *(const short8*)(&Pl[w][ln][lg * 8]);
#pragma unroll
  for (int nt4 = 0; nt4 < 4; ++nt4) {
    short8 vb = *(const short8*)(&Vt[w][nt4 * 16 + ln][lg * 8]);
    f32x4 acc = {0.f, 0.f, 0.f, 0.f};
    acc = __builtin_amdgcn_mfma_f32_16x16x32_bf16(pa, vb, acc, 0, 0, 0);
#pragma unroll
    for (int r = 0; r < 4; ++r) {
      int tq = lg * 4 + r;
      attn[((size_t)b * 3136 + (size_t)tq * 196 + p) * 768 + h * 64 + nt4 * 16 + ln] = f2b(acc[r]);
    }
  }
}

// ---------- launch ----------
extern "C" void kernel_launch(void* const* d_in, const int* in_sizes, int n_in,
                              void* d_out, int out_size, void* d_ws, size_t ws_size,
                              hipStream_t stream) {
  const float* x  = (const float*)d_in[0];
  const float* Wq = (const float*)d_in[1];
  const float* bq = (const float*)d_in[2];
  const float* Wk = (const float*)d_in[3];
  const float* bk = (const float*)d_in[4];
  const float* Wv = (const float*)d_in[5];
  const float* bv = (const float*)d_in[6];
  const float* Wo = (const float*)d_in[7];
  const float* bo = (const float*)d_in[8];
  float* out = (float*)d_out;
  char* ws = (char*)d_ws;
  unsigned short* xb    = (unsigned short*)(ws + 0);          // 25088*768*2
  unsigned short* wqkvT = (unsigned short*)(ws + 38535168);   // 2304*768*2
  float*          bqkv  = (float*)(ws + 42074112);            // 2304*4
  unsigned short* woT   = (unsigned short*)(ws + 42083328);   // 768*768*2
  unsigned short* qkvb  = (unsigned short*)(ws + 43262976);   // 25088*2304*2
  unsigned short* attnb = (unsigned short*)(ws + 158868480);  // 25088*768*2

  k_convert_x<<<18816, 256, 0, stream>>>(x, xb, bq, bk, bv, bqkv);
  k_pack_w<<<2304, 256, 0, stream>>>(Wq, Wk, Wv, Wo, wqkvT, woT);
  k_gemm256<<<882, 512, 0, stream>>>(xb, wqkvT, bqkv, qkvb, 25088, 2304);
  k_attn_spatial<<<768, 256, 0, stream>>>(qkvb, attnb);
  k_attn_temporal<<<2352, 256, 0, stream>>>(qkvb, attnb);
  k_gemm_out<<<dim3(6, 196), 256, 0, stream>>>(attnb, woT, bo, out, 25088, 768, 768);
}